// Round 17
// baseline (293.517 us; speedup 1.0000x reference)
//
#include <hip/hip_runtime.h>
#include <hip/hip_bf16.h>

// PoseRefinerModel: ST-GCN-like. bf16 MFMA datapath for gconv/agg/tconv.
// N=16 T=512 V=33 C=3 H=64, EPS=1e-5.
// Round 17 = round-16 (best passing, 288.4us) + 4-way nt-batching in
// k_stageA_b1 and k_stageA_b5 (adjacency/weight staging amortized 4x, thread
// utilization up, grid 8192->2048). Identical arithmetic, same barrier count.
// stageB / stageA_mfma / b5B / prep byte-identical to round 16.

constexpr int N_ = 16, T_ = 512, V_ = 33, C_ = 3, H_ = 64;
constexpr float EPS_ = 1e-5f;

typedef __attribute__((ext_vector_type(8))) short short8;
typedef __attribute__((ext_vector_type(4))) float f32x4;

__device__ inline unsigned short f2bf(float f) {
    union { __hip_bfloat16 h; unsigned short u; } cv;
    cv.h = __float2bfloat16(f);
    return cv.u;
}
__device__ inline float bf2f(unsigned short u) {
    union { unsigned short u; __hip_bfloat16 h; } cv;
    cv.u = u;
    return __bfloat162float(cv.h);
}

// ---------------- prep: bf16 weight re-layouts + padded bf16 adjacency ----------------
__global__ __launch_bounds__(256) void k_prep(
    const float* __restrict__ b1_tw, const float* __restrict__ m_tw,
    const float* __restrict__ b1_gw, const float* __restrict__ m_gw,
    const float* __restrict__ Adj,
    unsigned short* __restrict__ wT_bf, unsigned short* __restrict__ gw_bf,
    unsigned short* __restrict__ ATbf, float* __restrict__ colsum,
    float* __restrict__ gwT_b1)
{
    int idx = blockIdx.x * 256 + threadIdx.x;
    if (idx < 147456) {
        int s = idx / 36864, r = idx % 36864;
        int k = r / 4096, o = (r % 4096) / 64, i = r % 64;
        const float* src = (s == 0) ? b1_tw : (m_tw + (size_t)(s - 1) * 36864);
        wT_bf[idx] = f2bf(src[(o * 64 + i) * 9 + k]);
    } else if (idx < 147456 + 12288) {
        int r = idx - 147456;
        gw_bf[r] = f2bf(m_gw[r]);                 // already [s][o][c]
    } else if (idx < 147456 + 12288 + 3456) {
        int r = idx - 159744;
        int w = r / 72, vv = r % 72;
        ATbf[r] = (w < 33 && vv < 33) ? f2bf(Adj[vv * 33 + w]) : (unsigned short)0;
    } else if (idx < 147456 + 12288 + 3456 + 48) {
        int w = idx - 163200;
        float s = 0.f;
        if (w < 33)
            for (int vv = 0; vv < 33; ++vv) s += Adj[vv * 33 + w];
        colsum[w] = s;
    } else if (idx < 147456 + 12288 + 3456 + 48 + 192) {
        int r = idx - 163248;
        int c = r / 64, o = r % 64;
        gwT_b1[r] = b1_gw[o * 3 + c];
    }
}

// ---------------- b1 stage A (+fused data_bn): gconv 3->64 + agg + BN1 + ReLU ----------
// 4 (n,t) per block: adjacency/gw staged once, work loops 4x wider.
__global__ __launch_bounds__(256) void k_stageA_b1(
    const float* __restrict__ x,    // [N,T,V,3] f32 RAW input (data_bn applied inline)
    unsigned short* __restrict__ out, // [N,T,V,64] bf16
    const float* __restrict__ Adj,
    const float* __restrict__ gwT,  // [3][64] f32
    const float* __restrict__ gb,
    const float* __restrict__ g1, const float* __restrict__ b1,
    const float* __restrict__ m1, const float* __restrict__ v1,
    const float* __restrict__ dg, const float* __restrict__ db,
    const float* __restrict__ dm, const float* __restrict__ dv)
{
    __shared__ float sy[4][V_ * 4];
    __shared__ float su[4][V_ * 68];
    __shared__ float sA[V_ * V_];
    __shared__ float sgwT[3 * 64];

    int nt0 = blockIdx.x * 4;
    int tid = threadIdx.x;
    // fused data_bn staging for 4 nt: param index jj = c*V + ((t*V+v)>>9)
    for (int idx = tid; idx < 4 * V_ * 3; idx += 256) {
        int j = idx / (V_ * 3), r = idx % (V_ * 3);
        int v = r / 3, c = r % 3;
        int nt = nt0 + j;
        int t = nt & (T_ - 1);
        int jj = c * V_ + ((t * V_ + v) >> 9);
        float s = dg[jj] * rsqrtf(dv[jj] + EPS_);
        sy[j][v * 4 + c] = (x[(size_t)nt * (V_ * 3) + r] - dm[jj]) * s + db[jj];
    }
    for (int idx = tid; idx < V_ * V_; idx += 256) sA[idx] = Adj[idx];
    for (int idx = tid; idx < 3 * 64; idx += 256) sgwT[idx] = gwT[idx];
    __syncthreads();

    for (int idx = tid; idx < 4 * V_ * 16; idx += 256) {
        int j = idx / (V_ * 16), r = idx % (V_ * 16);
        int v = r >> 4, oq = r & 15, o4 = oq * 4;
        float a0 = gb[o4], a1 = gb[o4 + 1], a2 = gb[o4 + 2], a3 = gb[o4 + 3];
#pragma unroll
        for (int c = 0; c < 3; ++c) {
            float yv = sy[j][v * 4 + c];
            const float4 w4 = *reinterpret_cast<const float4*>(&sgwT[c * 64 + o4]);
            a0 = fmaf(yv, w4.x, a0); a1 = fmaf(yv, w4.y, a1);
            a2 = fmaf(yv, w4.z, a2); a3 = fmaf(yv, w4.w, a3);
        }
        *reinterpret_cast<float4*>(&su[j][v * 68 + o4]) = make_float4(a0, a1, a2, a3);
    }
    __syncthreads();

    for (int idx = tid; idx < 4 * V_ * 16; idx += 256) {
        int j = idx / (V_ * 16), r = idx % (V_ * 16);
        int w = r >> 4, oq = r & 15, o4 = oq * 4;
        float a0 = 0.f, a1 = 0.f, a2 = 0.f, a3 = 0.f;
        for (int v = 0; v < V_; ++v) {
            float av = sA[v * V_ + w];
            const float4 u4 = *reinterpret_cast<const float4*>(&su[j][v * 68 + o4]);
            a0 = fmaf(av, u4.x, a0); a1 = fmaf(av, u4.y, a1);
            a2 = fmaf(av, u4.z, a2); a3 = fmaf(av, u4.w, a3);
        }
        float acc[4] = {a0, a1, a2, a3};
        unsigned short r4[4];
#pragma unroll
        for (int q = 0; q < 4; ++q) {
            int o = o4 + q;
            float s = g1[o] * rsqrtf(v1[o] + EPS_);
            float tt = b1[o] - m1[o] * s;
            r4[q] = f2bf(fmaxf(fmaf(acc[q], s, tt), 0.f));
        }
        *reinterpret_cast<ushort4*>(
            &out[(size_t)(nt0 + j) * (V_ * 64) + w * 64 + o4]) =
            *reinterpret_cast<ushort4*>(r4);
    }
}

// ---------------- mid stage A: gconv 64->64 + agg + BN1 + ReLU via MFMA ----------------
// 4 (n,t) pairs per block, 4 waves (each owns a 16-wide o slice). Ys staged
// coalesced into LDS; per-j barriers removed (UT rows wave-private). (round-14)
__global__ __launch_bounds__(256) void k_stageA_mfma(
    const unsigned short* __restrict__ in,   // [N,T,V,64] bf16
    unsigned short* __restrict__ out,        // [N,T,V,64] bf16
    const unsigned short* __restrict__ ATbf, // [48][72] bf16
    const float* __restrict__ colsum,        // [48]
    const unsigned short* __restrict__ gwbf, // [64][64] bf16 [o][c]
    const float* __restrict__ gb,
    const float* __restrict__ g1, const float* __restrict__ b1,
    const float* __restrict__ m1, const float* __restrict__ v1)
{
    __shared__ unsigned short Ys[4 * 48 * 72];
    __shared__ unsigned short UT[64 * 72];
    __shared__ float cs[48];

    int nt0 = blockIdx.x * 4;
    int tid = threadIdx.x;
    int wv = tid >> 6, lane = tid & 63;
    int l15 = lane & 15, lg = lane >> 4;
    int o = wv * 16 + l15;

    // preload fragments (registers)
    short8 atf[3][2];
#pragma unroll
    for (int mf = 0; mf < 3; ++mf)
#pragma unroll
        for (int kk = 0; kk < 2; ++kk)
            atf[mf][kk] = *reinterpret_cast<const short8*>(
                ATbf + (16 * mf + l15) * 72 + kk * 32 + lg * 8);
    short8 gwf[2];
#pragma unroll
    for (int kk = 0; kk < 2; ++kk)
        gwf[kk] = *reinterpret_cast<const short8*>(gwbf + o * 64 + kk * 32 + lg * 8);

    float gbl = gb[o];
    float s1 = g1[o] * rsqrtf(v1[o] + EPS_);
    float c1 = b1[o] - m1[o] * s1;

    // stage Ys (4 nt x 33 rows x 64 ch), pad rows 33..47 with zeros
    for (int idx = tid; idx < 1056; idx += 256) {
        int j = idx / 264, r = idx % 264;
        int v = r >> 3, cc = r & 7;
        *reinterpret_cast<short8*>(&Ys[(j * 48 + v) * 72 + cc * 8]) =
            *reinterpret_cast<const short8*>(in + ((size_t)(nt0 + j) * V_ + v) * 64 + cc * 8);
    }
    for (int idx = tid; idx < 540; idx += 256) {
        int j = idx / 135, r = idx % 135;
        int v = 33 + r / 9, cc = r % 9;
        short8 z = {};
        *reinterpret_cast<short8*>(&Ys[(j * 48 + v) * 72 + cc * 8]) = z;
    }
    // zero UT v=48..63 (read by GEMM2 K-pad; written once, read-only after barrier)
    for (int idx = tid; idx < 128; idx += 256) {
        int oo = idx >> 1, cc = idx & 1;
        short8 z = {};
        *reinterpret_cast<short8*>(&UT[oo * 72 + 48 + cc * 8]) = z;
    }
    if (tid < 48) cs[tid] = colsum[tid];
    __syncthreads();   // the ONLY block-wide barrier

    for (int j = 0; j < 4; ++j) {
        // GEMM1: U[v][o] = sum_c Y[v][c] * gw[o][c]; write U^T[o][v] bf16 to LDS.
#pragma unroll
        for (int mf = 0; mf < 3; ++mf) {
            f32x4 au = {};
#pragma unroll
            for (int kk = 0; kk < 2; ++kk) {
                short8 a = *reinterpret_cast<const short8*>(
                    &Ys[(j * 48 + 16 * mf + l15) * 72 + kk * 32 + lg * 8]);
                au = __builtin_amdgcn_mfma_f32_16x16x32_bf16(a, gwf[kk], au, 0, 0, 0);
            }
            unsigned short pk[4];
            pk[0] = f2bf(au[0]); pk[1] = f2bf(au[1]);
            pk[2] = f2bf(au[2]); pk[3] = f2bf(au[3]);
            *reinterpret_cast<ushort4*>(&UT[o * 72 + 16 * mf + lg * 4]) =
                *reinterpret_cast<ushort4*>(pk);
        }
        // GEMM2: Z[w][o] = sum_v AT[w][v] * U[v][o]
        short8 bu[2];
#pragma unroll
        for (int kk = 0; kk < 2; ++kk)
            bu[kk] = *reinterpret_cast<const short8*>(&UT[o * 72 + kk * 32 + lg * 8]);
#pragma unroll
        for (int mf2 = 0; mf2 < 3; ++mf2) {
            f32x4 az = {};
#pragma unroll
            for (int kk = 0; kk < 2; ++kk)
                az = __builtin_amdgcn_mfma_f32_16x16x32_bf16(atf[mf2][kk], bu[kk], az, 0, 0, 0);
#pragma unroll
            for (int r = 0; r < 4; ++r) {
                int w = 16 * mf2 + lg * 4 + r;
                if (w < 33) {
                    float val = az[r] + gbl * cs[w];
                    float y = fmaxf(val * s1 + c1, 0.f);
                    out[((size_t)(nt0 + j) * V_ + w) * 64 + o] = f2bf(y);
                }
            }
        }
    }
}

// ---------------- stage B: 9x1 tconv (64->64) + BN2 (+res) + ReLU via MFMA ----------------
// Round-6/10 version (measured floor 47us): persistent t-march depth 4,
// double-buffered swizzled LDS, reg-staged issue-early/write-late, hoisted residual.
template <bool RES>
__global__ __launch_bounds__(256) void k_stageB_mfma(
    const unsigned short* __restrict__ z,   // [N,T,V,64] bf16 conv input
    unsigned short* __restrict__ out,       // [N,T,V,64] bf16 (residual source if RES)
    const unsigned short* __restrict__ wbf, // [9][64][64] bf16 [k][o][i]
    const float* __restrict__ tb,
    const float* __restrict__ g2, const float* __restrict__ b2,
    const float* __restrict__ m2, const float* __restrict__ vv2)
{
    __shared__ unsigned short sa[2][72 * 64];  // two swizzled tile buffers

    int bx = blockIdx.x, v = blockIdx.y, n = blockIdx.z;
    int base_t0 = bx * 256;                    // block covers t in [base_t0, base_t0+256)
    int tid = threadIdx.x;
    int wv = tid >> 6, lane = tid & 63;
    int l15 = lane & 15, lg = lane >> 4;
    int o = wv * 16 + l15;

    // preload 18 weight fragments into registers
    short8 bw[18];
#pragma unroll
    for (int k = 0; k < 9; ++k)
#pragma unroll
        for (int c = 0; c < 2; ++c)
            bw[k * 2 + c] = *reinterpret_cast<const short8*>(
                wbf + ((k * 64 + o) * 64) + c * 32 + lg * 8);

    float s2 = g2[o] * rsqrtf(vv2[o] + EPS_);
    float c2 = (tb[o] - m2[o]) * s2 + b2[o];

    // staging regs: each thread covers idx = tid, tid+256, tid+512 (<576)
    short8 stg[3];

#define LOADJ(jj)                                                             \
    {                                                                         \
        int t0l = base_t0 + (jj) * 64;                                        \
        _Pragma("unroll")                                                     \
        for (int it = 0; it < 3; ++it) {                                      \
            int idx = tid + it * 256;                                         \
            if (idx < 576) {                                                  \
                int r = idx >> 3;                                             \
                int tg = t0l - 4 + r;                                         \
                short8 val = {};                                              \
                if (tg >= 0 && tg < T_)                                       \
                    val = *reinterpret_cast<const short8*>(                   \
                        z + ((size_t)(n * T_ + tg) * V_ + v) * 64 +           \
                        (idx & 7) * 8);                                       \
                stg[it] = val;                                                \
            }                                                                 \
        }                                                                     \
    }

#define WRITEJ(pp)                                                            \
    {                                                                         \
        _Pragma("unroll")                                                     \
        for (int it = 0; it < 3; ++it) {                                      \
            int idx = tid + it * 256;                                         \
            if (idx < 576) {                                                  \
                int r = idx >> 3, cc = idx & 7;                               \
                int slot = cc ^ (r & 7);                                      \
                *reinterpret_cast<short8*>(                                   \
                    reinterpret_cast<char*>(&sa[pp][0]) + r * 128 +           \
                    slot * 16) = stg[it];                                     \
            }                                                                 \
        }                                                                     \
    }

    // prologue: stage tile 0 into buffer 0
    LOADJ(0);
    WRITEJ(0);
    __syncthreads();

    int p = 0;
    for (int j = 0; j < 4; ++j) {
        // issue next tile's global loads early (latency hides under compute)
        if (j < 3) LOADJ(j + 1);

        int t0 = base_t0 + j * 64;

        // hoist residual loads (same-thread RAW with own later store: safe)
        unsigned short res[16];
        if (RES) {
#pragma unroll
            for (int f = 0; f < 4; ++f)
#pragma unroll
                for (int r = 0; r < 4; ++r) {
                    int t = t0 + f * 16 + lg * 4 + r;
                    res[f * 4 + r] =
                        out[((size_t)(n * T_ + t) * V_ + v) * 64 + o];
                }
        }

        // compute tile j from sa[p]
        f32x4 acc[4] = {};
        for (int k = 0; k < 9; ++k) {
#pragma unroll
            for (int c = 0; c < 2; ++c) {
                short8 b = bw[k * 2 + c];
#pragma unroll
                for (int f = 0; f < 4; ++f) {
                    int r = f * 16 + l15 + k;
                    int slot = (c * 4 + lg) ^ (r & 7);
                    short8 a = *reinterpret_cast<const short8*>(
                        reinterpret_cast<const char*>(&sa[p][0]) + r * 128 + slot * 16);
                    acc[f] = __builtin_amdgcn_mfma_f32_16x16x32_bf16(a, b, acc[f], 0, 0, 0);
                }
            }
        }

        // epilogue for tile j
#pragma unroll
        for (int f = 0; f < 4; ++f) {
#pragma unroll
            for (int r = 0; r < 4; ++r) {
                int t = t0 + f * 16 + lg * 4 + r;
                size_t addr = ((size_t)(n * T_ + t) * V_ + v) * 64 + o;
                float zz = acc[f][r] * s2 + c2;
                if (RES) zz += bf2f(res[f * 4 + r]);
                out[addr] = f2bf(fmaxf(zz, 0.f));
            }
        }

        // write staged regs into the other buffer, then one barrier
        if (j < 3) WRITEJ(p ^ 1);
        __syncthreads();
        p ^= 1;
    }
#undef LOADJ
#undef WRITEJ
}

// ---------------- b5 stage A: gconv 64->3 + agg + BN1 + ReLU (bf16 in, f32 out) ----------
// 4 (n,t) per block: adjacency staged once, work loops 4x wider.
__global__ __launch_bounds__(256) void k_stageA_b5(
    const unsigned short* __restrict__ in,  // [N,T,V,64] bf16
    float* __restrict__ out,                // [N,T,V,3] f32
    const float* __restrict__ Adj,
    const float* __restrict__ gw,           // [3][64]
    const float* __restrict__ gb,
    const float* __restrict__ g1, const float* __restrict__ b1,
    const float* __restrict__ m1, const float* __restrict__ v1)
{
    __shared__ float sy[4][V_ * 64];
    __shared__ float su[4][V_ * 4];
    __shared__ float sA[V_ * V_];
    int nt0 = blockIdx.x * 4;
    int tid = threadIdx.x;
    for (int idx = tid; idx < 4 * 264; idx += 256) {
        int j = idx / 264, r = idx % 264;
        short8 val = *reinterpret_cast<const short8*>(
            in + (size_t)(nt0 + j) * (V_ * 64) + r * 8);
#pragma unroll
        for (int e = 0; e < 8; ++e)
            sy[j][r * 8 + e] = bf2f((unsigned short)val[e]);
    }
    for (int idx = tid; idx < V_ * V_; idx += 256) sA[idx] = Adj[idx];
    __syncthreads();
    for (int idx = tid; idx < 4 * V_ * 3; idx += 256) {
        int j = idx / (V_ * 3), r = idx % (V_ * 3);
        int v = r / 3, o = r % 3;
        float a = gb[o];
        for (int c = 0; c < 64; ++c) a = fmaf(sy[j][v * 64 + c], gw[o * 64 + c], a);
        su[j][v * 4 + o] = a;
    }
    __syncthreads();
    for (int idx = tid; idx < 4 * V_ * 3; idx += 256) {
        int j = idx / (V_ * 3), r = idx % (V_ * 3);
        int w = r / 3, o = r % 3;
        float a = 0.f;
        for (int vv = 0; vv < V_; ++vv) a = fmaf(su[j][vv * 4 + o], sA[vv * V_ + w], a);
        float s = g1[o] * rsqrtf(v1[o] + EPS_);
        float zz = (a - m1[o]) * s + b1[o];
        out[(size_t)(nt0 + j) * (V_ * 3) + w * 3 + o] = fmaxf(zz, 0.f);
    }
}

// ---------------- b5 stage B: tconv 3->3 + BN2 + ReLU, + raw x, write d_out ----------------
__global__ __launch_bounds__(256) void k_stageB_b5(
    const float* __restrict__ z5,   // [N,T,V,3]
    const float* __restrict__ x,    // [N,T,V,3]
    float* __restrict__ out,        // [N,T,V,3]
    const float* __restrict__ tw,   // [3][3][9]
    const float* __restrict__ tb,
    const float* __restrict__ g2, const float* __restrict__ b2,
    const float* __restrict__ m2, const float* __restrict__ v2)
{
    int idx = blockIdx.x * 256 + threadIdx.x;  // over N*T*V
    if (idx >= N_ * T_ * V_) return;
    int v = idx % V_;
    int t = (idx / V_) % T_;
    int n = idx / (V_ * T_);
    float acc0 = tb[0], acc1 = tb[1], acc2 = tb[2];
    for (int k = 0; k < 9; ++k) {
        int tg = t + k - 4;
        if (tg < 0 || tg >= T_) continue;
        const float* zp = &z5[((size_t)(n * T_ + tg) * V_ + v) * 3];
        float zi0 = zp[0], zi1 = zp[1], zi2 = zp[2];
        acc0 = fmaf(tw[0 * 9 + k], zi0, acc0);
        acc0 = fmaf(tw[1 * 9 + k], zi1, acc0);
        acc0 = fmaf(tw[2 * 9 + k], zi2, acc0);
        acc1 = fmaf(tw[3 * 9 + k], zi0, acc1);
        acc1 = fmaf(tw[4 * 9 + k], zi1, acc1);
        acc1 = fmaf(tw[5 * 9 + k], zi2, acc1);
        acc2 = fmaf(tw[6 * 9 + k], zi0, acc2);
        acc2 = fmaf(tw[7 * 9 + k], zi1, acc2);
        acc2 = fmaf(tw[8 * 9 + k], zi2, acc2);
    }
    size_t base = (size_t)idx * 3;
    float a[3] = {acc0, acc1, acc2};
#pragma unroll
    for (int oo = 0; oo < 3; ++oo) {
        float s = g2[oo] * rsqrtf(v2[oo] + EPS_);
        float zz = (a[oo] - m2[oo]) * s + b2[oo];
        out[base + oo] = x[base + oo] + fmaxf(zz, 0.f);
    }
}

extern "C" void kernel_launch(void* const* d_in, const int* in_sizes, int n_in,
                              void* d_out, int out_size, void* d_ws, size_t ws_size,
                              hipStream_t stream) {
    int a = 0;
    const float* x      = (const float*)d_in[a++];
    const float* Adj    = (const float*)d_in[a++];
    const float* dbn_g  = (const float*)d_in[a++];
    const float* dbn_b  = (const float*)d_in[a++];
    const float* dbn_m  = (const float*)d_in[a++];
    const float* dbn_v  = (const float*)d_in[a++];
    const float* b1_gw  = (const float*)d_in[a++];
    const float* b1_gb  = (const float*)d_in[a++];
    const float* b1_bn1g = (const float*)d_in[a++];
    const float* b1_bn1b = (const float*)d_in[a++];
    const float* b1_bn1m = (const float*)d_in[a++];
    const float* b1_bn1v = (const float*)d_in[a++];
    const float* b1_tw  = (const float*)d_in[a++];
    const float* b1_tb  = (const float*)d_in[a++];
    const float* b1_bn2g = (const float*)d_in[a++];
    const float* b1_bn2b = (const float*)d_in[a++];
    const float* b1_bn2m = (const float*)d_in[a++];
    const float* b1_bn2v = (const float*)d_in[a++];
    const float* m_gw   = (const float*)d_in[a++];
    const float* m_gb   = (const float*)d_in[a++];
    const float* m_bn1g = (const float*)d_in[a++];
    const float* m_bn1b = (const float*)d_in[a++];
    const float* m_bn1m = (const float*)d_in[a++];
    const float* m_bn1v = (const float*)d_in[a++];
    const float* m_tw   = (const float*)d_in[a++];
    const float* m_tb   = (const float*)d_in[a++];
    const float* m_bn2g = (const float*)d_in[a++];
    const float* m_bn2b = (const float*)d_in[a++];
    const float* m_bn2m = (const float*)d_in[a++];
    const float* m_bn2v = (const float*)d_in[a++];
    const float* b5_gw  = (const float*)d_in[a++];
    const float* b5_gb  = (const float*)d_in[a++];
    const float* b5_bn1g = (const float*)d_in[a++];
    const float* b5_bn1b = (const float*)d_in[a++];
    const float* b5_bn1m = (const float*)d_in[a++];
    const float* b5_bn1v = (const float*)d_in[a++];
    const float* b5_tw  = (const float*)d_in[a++];
    const float* b5_tb  = (const float*)d_in[a++];
    const float* b5_bn2g = (const float*)d_in[a++];
    const float* b5_bn2b = (const float*)d_in[a++];
    const float* b5_bn2m = (const float*)d_in[a++];
    const float* b5_bn2v = (const float*)d_in[a++];

    // ws layout (bytes, all 16B aligned)
    char* ws = (char*)d_ws;
    const size_t S_BIG_B  = (size_t)N_ * T_ * V_ * 64 * 2;   // bf16 big buffers
    const size_t S_SM_B   = (size_t)N_ * T_ * V_ * 3 * 4;    // f32 small buffers
    unsigned short* B0     = (unsigned short*)(ws);
    unsigned short* B1     = (unsigned short*)(ws + S_BIG_B);
    float*          z5     = (float*)(ws + 2 * S_BIG_B + S_SM_B);
    unsigned short* wT_bf  = (unsigned short*)(ws + 2 * S_BIG_B + 2 * S_SM_B);
    unsigned short* gw_bf  = wT_bf + 147456;
    unsigned short* ATbf   = gw_bf + 12288;
    float*          colsum = (float*)(ATbf + 3456);
    float*          gwT_b1 = colsum + 48;

    k_prep<<<(163440 + 255) / 256, 256, 0, stream>>>(
        b1_tw, m_tw, b1_gw, m_gw, Adj, wT_bf, gw_bf, ATbf, colsum, gwT_b1);

    // b1: 3 -> 64 (VALU, data_bn fused, 4 nt/block), tconv via MFMA, no residual
    k_stageA_b1<<<(N_ * T_) / 4, 256, 0, stream>>>(
        x, B1, Adj, gwT_b1, b1_gb, b1_bn1g, b1_bn1b, b1_bn1m, b1_bn1v,
        dbn_g, dbn_b, dbn_m, dbn_v);
    k_stageB_mfma<false><<<dim3(T_ / 256, V_, N_), 256, 0, stream>>>(
        B1, B0, wT_bf, b1_tb, b1_bn2g, b1_bn2b, b1_bn2m, b1_bn2v);

    // 3 mid blocks: 64 -> 64 MFMA, residual (in-place into B0)
    for (int i = 0; i < 3; ++i) {
        k_stageA_mfma<<<(N_ * T_) / 4, 256, 0, stream>>>(
            B0, B1, ATbf, colsum, gw_bf + i * 4096, m_gb + i * 64,
            m_bn1g + i * 64, m_bn1b + i * 64, m_bn1m + i * 64, m_bn1v + i * 64);
        k_stageB_mfma<true><<<dim3(T_ / 256, V_, N_), 256, 0, stream>>>(
            B1, B0, wT_bf + (1 + i) * 36864, m_tb + i * 64,
            m_bn2g + i * 64, m_bn2b + i * 64, m_bn2m + i * 64, m_bn2v + i * 64);
    }

    // b5: 64 -> 3 (4 nt/block), no residual; then + raw x, write d_out
    k_stageA_b5<<<(N_ * T_) / 4, 256, 0, stream>>>(
        B0, z5, Adj, b5_gw, b5_gb, b5_bn1g, b5_bn1b, b5_bn1m, b5_bn1v);
    k_stageB_b5<<<(N_ * T_ * V_ + 255) / 256, 256, 0, stream>>>(
        z5, x, (float*)d_out, b5_tw, b5_tb, b5_bn2g, b5_bn2b, b5_bn2m, b5_bn2v);
}

// Round 18
// 270.309 us; speedup vs baseline: 1.0859x; 1.0859x over previous
//
#include <hip/hip_runtime.h>
#include <hip/hip_bf16.h>

// PoseRefinerModel: ST-GCN-like. bf16 MFMA datapath for gconv/agg/tconv.
// N=16 T=512 V=33 C=3 H=64, EPS=1e-5.
// Round 18 = round-16 base (288.4us) with k_stageA_b1 rewritten:
//   VALU gconv (K=3) -> UT bf16 -> MFMA aggregation (stageA_mfma's proven
//   GEMM2: atf frags, colsum bias, wave-private UT, barrier-free j-loop).
//   Profile showed old b1A was ~45-49us: MfmaUtil=0, 33-deep serial VALU agg.
// b5A reverted to round-16 unbatched. stageB/stageA_mfma/b5B/prep = round 16.

constexpr int N_ = 16, T_ = 512, V_ = 33, C_ = 3, H_ = 64;
constexpr float EPS_ = 1e-5f;

typedef __attribute__((ext_vector_type(8))) short short8;
typedef __attribute__((ext_vector_type(4))) float f32x4;

__device__ inline unsigned short f2bf(float f) {
    union { __hip_bfloat16 h; unsigned short u; } cv;
    cv.h = __float2bfloat16(f);
    return cv.u;
}
__device__ inline float bf2f(unsigned short u) {
    union { unsigned short u; __hip_bfloat16 h; } cv;
    cv.u = u;
    return __bfloat162float(cv.h);
}

// ---------------- prep: bf16 weight re-layouts + padded bf16 adjacency ----------------
__global__ __launch_bounds__(256) void k_prep(
    const float* __restrict__ b1_tw, const float* __restrict__ m_tw,
    const float* __restrict__ b1_gw, const float* __restrict__ m_gw,
    const float* __restrict__ Adj,
    unsigned short* __restrict__ wT_bf, unsigned short* __restrict__ gw_bf,
    unsigned short* __restrict__ ATbf, float* __restrict__ colsum,
    float* __restrict__ gwT_b1)
{
    int idx = blockIdx.x * 256 + threadIdx.x;
    if (idx < 147456) {
        int s = idx / 36864, r = idx % 36864;
        int k = r / 4096, o = (r % 4096) / 64, i = r % 64;
        const float* src = (s == 0) ? b1_tw : (m_tw + (size_t)(s - 1) * 36864);
        wT_bf[idx] = f2bf(src[(o * 64 + i) * 9 + k]);
    } else if (idx < 147456 + 12288) {
        int r = idx - 147456;
        gw_bf[r] = f2bf(m_gw[r]);                 // already [s][o][c]
    } else if (idx < 147456 + 12288 + 3456) {
        int r = idx - 159744;
        int w = r / 72, vv = r % 72;
        ATbf[r] = (w < 33 && vv < 33) ? f2bf(Adj[vv * 33 + w]) : (unsigned short)0;
    } else if (idx < 147456 + 12288 + 3456 + 48) {
        int w = idx - 163200;
        float s = 0.f;
        if (w < 33)
            for (int vv = 0; vv < 33; ++vv) s += Adj[vv * 33 + w];
        colsum[w] = s;
    } else if (idx < 147456 + 12288 + 3456 + 48 + 192) {
        int r = idx - 163248;
        int c = r / 64, o = r % 64;
        gwT_b1[r] = b1_gw[o * 3 + c];
    }
}

// ---------------- b1 stage A (+fused data_bn): gconv 3->64 + MFMA agg + BN1 + ReLU ----
// 4 (n,t) per block, 4 waves (each owns a 16-wide o slice).
// U computed via VALU (K=3), written bf16 to wave-private UT; aggregation via
// the stageA_mfma GEMM2 (atf frags, colsum bias); barrier-free j-loop.
__global__ __launch_bounds__(256) void k_stageA_b1(
    const float* __restrict__ x,    // [N,T,V,3] f32 RAW input (data_bn applied inline)
    unsigned short* __restrict__ out, // [N,T,V,64] bf16
    const unsigned short* __restrict__ ATbf, // [48][72] bf16
    const float* __restrict__ colsum,        // [48]
    const float* __restrict__ gwT,  // [3][64] f32 (c-major)
    const float* __restrict__ gb,
    const float* __restrict__ g1, const float* __restrict__ b1,
    const float* __restrict__ m1, const float* __restrict__ v1,
    const float* __restrict__ dg, const float* __restrict__ db,
    const float* __restrict__ dm, const float* __restrict__ dv)
{
    __shared__ float sy[4][V_ * 4];          // [j][v*4+c] data_bn'd input
    __shared__ unsigned short UT[64 * 72];   // [o][v] bf16, wave-private rows
    __shared__ float cs[48];

    int nt0 = blockIdx.x * 4;
    int tid = threadIdx.x;
    int wv = tid >> 6, lane = tid & 63;
    int l15 = lane & 15, lg = lane >> 4;
    int o = wv * 16 + l15;

    // aggregation B... A-frags (AT rows = w), identical to stageA_mfma
    short8 atf[3][2];
#pragma unroll
    for (int mf = 0; mf < 3; ++mf)
#pragma unroll
        for (int kk = 0; kk < 2; ++kk)
            atf[mf][kk] = *reinterpret_cast<const short8*>(
                ATbf + (16 * mf + l15) * 72 + kk * 32 + lg * 8);

    // per-lane gconv weights for this lane's o (K=3)
    float gw0 = gwT[0 * 64 + o], gw1 = gwT[1 * 64 + o], gw2 = gwT[2 * 64 + o];
    float gbl = gb[o];
    float s1 = g1[o] * rsqrtf(v1[o] + EPS_);
    float c1 = b1[o] - m1[o] * s1;

    // stage sy (4 nt x 33 v x 3 c) with fused data_bn
    for (int idx = tid; idx < 4 * V_ * 3; idx += 256) {
        int j = idx / (V_ * 3), r = idx % (V_ * 3);
        int v = r / 3, c = r % 3;
        int nt = nt0 + j;
        int t = nt & (T_ - 1);
        int jj = c * V_ + ((t * V_ + v) >> 9);
        float s = dg[jj] * rsqrtf(dv[jj] + EPS_);
        sy[j][v * 4 + c] = (x[(size_t)nt * (V_ * 3) + r] - dm[jj]) * s + db[jj];
    }
    // zero UT v=48..63 (K-pad; written once, read-only after barrier)
    for (int idx = tid; idx < 128; idx += 256) {
        int oo = idx >> 1, cc = idx & 1;
        short8 z = {};
        *reinterpret_cast<short8*>(&UT[oo * 72 + 48 + cc * 8]) = z;
    }
    if (tid < 48) cs[tid] = colsum[tid];
    __syncthreads();   // the ONLY block-wide barrier

    for (int j = 0; j < 4; ++j) {
        // U[v][o] = sum_c y[v][c]*gw[c][o]; UT row o written by this wave only.
        // Lane covers v = lg, lg+4, ..., lg+44 (12 values; v>=33 -> 0).
#pragma unroll
        for (int it = 0; it < 12; ++it) {
            int v = lg + it * 4;
            float u = 0.f;
            if (v < V_) {
                u = sy[j][v * 4 + 0] * gw0;
                u = fmaf(sy[j][v * 4 + 1], gw1, u);
                u = fmaf(sy[j][v * 4 + 2], gw2, u);
            }
            UT[o * 72 + v] = f2bf(u);
        }
        // aggregation: Z[w][o] = sum_v AT[w][v] * U[v][o]  (stageA_mfma GEMM2)
        short8 bu[2];
#pragma unroll
        for (int kk = 0; kk < 2; ++kk)
            bu[kk] = *reinterpret_cast<const short8*>(&UT[o * 72 + kk * 32 + lg * 8]);
#pragma unroll
        for (int mf2 = 0; mf2 < 3; ++mf2) {
            f32x4 az = {};
#pragma unroll
            for (int kk = 0; kk < 2; ++kk)
                az = __builtin_amdgcn_mfma_f32_16x16x32_bf16(atf[mf2][kk], bu[kk], az, 0, 0, 0);
#pragma unroll
            for (int r = 0; r < 4; ++r) {
                int w = 16 * mf2 + lg * 4 + r;
                if (w < 33) {
                    float val = az[r] + gbl * cs[w];
                    float y = fmaxf(val * s1 + c1, 0.f);
                    out[((size_t)(nt0 + j) * V_ + w) * 64 + o] = f2bf(y);
                }
            }
        }
    }
}

// ---------------- mid stage A: gconv 64->64 + agg + BN1 + ReLU via MFMA ----------------
// 4 (n,t) pairs per block, 4 waves (each owns a 16-wide o slice). Ys staged
// coalesced into LDS; per-j barriers removed (UT rows wave-private). (round-14)
__global__ __launch_bounds__(256) void k_stageA_mfma(
    const unsigned short* __restrict__ in,   // [N,T,V,64] bf16
    unsigned short* __restrict__ out,        // [N,T,V,64] bf16
    const unsigned short* __restrict__ ATbf, // [48][72] bf16
    const float* __restrict__ colsum,        // [48]
    const unsigned short* __restrict__ gwbf, // [64][64] bf16 [o][c]
    const float* __restrict__ gb,
    const float* __restrict__ g1, const float* __restrict__ b1,
    const float* __restrict__ m1, const float* __restrict__ v1)
{
    __shared__ unsigned short Ys[4 * 48 * 72];
    __shared__ unsigned short UT[64 * 72];
    __shared__ float cs[48];

    int nt0 = blockIdx.x * 4;
    int tid = threadIdx.x;
    int wv = tid >> 6, lane = tid & 63;
    int l15 = lane & 15, lg = lane >> 4;
    int o = wv * 16 + l15;

    // preload fragments (registers)
    short8 atf[3][2];
#pragma unroll
    for (int mf = 0; mf < 3; ++mf)
#pragma unroll
        for (int kk = 0; kk < 2; ++kk)
            atf[mf][kk] = *reinterpret_cast<const short8*>(
                ATbf + (16 * mf + l15) * 72 + kk * 32 + lg * 8);
    short8 gwf[2];
#pragma unroll
    for (int kk = 0; kk < 2; ++kk)
        gwf[kk] = *reinterpret_cast<const short8*>(gwbf + o * 64 + kk * 32 + lg * 8);

    float gbl = gb[o];
    float s1 = g1[o] * rsqrtf(v1[o] + EPS_);
    float c1 = b1[o] - m1[o] * s1;

    // stage Ys (4 nt x 33 rows x 64 ch), pad rows 33..47 with zeros
    for (int idx = tid; idx < 1056; idx += 256) {
        int j = idx / 264, r = idx % 264;
        int v = r >> 3, cc = r & 7;
        *reinterpret_cast<short8*>(&Ys[(j * 48 + v) * 72 + cc * 8]) =
            *reinterpret_cast<const short8*>(in + ((size_t)(nt0 + j) * V_ + v) * 64 + cc * 8);
    }
    for (int idx = tid; idx < 540; idx += 256) {
        int j = idx / 135, r = idx % 135;
        int v = 33 + r / 9, cc = r % 9;
        short8 z = {};
        *reinterpret_cast<short8*>(&Ys[(j * 48 + v) * 72 + cc * 8]) = z;
    }
    // zero UT v=48..63 (read by GEMM2 K-pad; written once, read-only after barrier)
    for (int idx = tid; idx < 128; idx += 256) {
        int oo = idx >> 1, cc = idx & 1;
        short8 z = {};
        *reinterpret_cast<short8*>(&UT[oo * 72 + 48 + cc * 8]) = z;
    }
    if (tid < 48) cs[tid] = colsum[tid];
    __syncthreads();   // the ONLY block-wide barrier

    for (int j = 0; j < 4; ++j) {
        // GEMM1: U[v][o] = sum_c Y[v][c] * gw[o][c]; write U^T[o][v] bf16 to LDS.
#pragma unroll
        for (int mf = 0; mf < 3; ++mf) {
            f32x4 au = {};
#pragma unroll
            for (int kk = 0; kk < 2; ++kk) {
                short8 a = *reinterpret_cast<const short8*>(
                    &Ys[(j * 48 + 16 * mf + l15) * 72 + kk * 32 + lg * 8]);
                au = __builtin_amdgcn_mfma_f32_16x16x32_bf16(a, gwf[kk], au, 0, 0, 0);
            }
            unsigned short pk[4];
            pk[0] = f2bf(au[0]); pk[1] = f2bf(au[1]);
            pk[2] = f2bf(au[2]); pk[3] = f2bf(au[3]);
            *reinterpret_cast<ushort4*>(&UT[o * 72 + 16 * mf + lg * 4]) =
                *reinterpret_cast<ushort4*>(pk);
        }
        // GEMM2: Z[w][o] = sum_v AT[w][v] * U[v][o]
        short8 bu[2];
#pragma unroll
        for (int kk = 0; kk < 2; ++kk)
            bu[kk] = *reinterpret_cast<const short8*>(&UT[o * 72 + kk * 32 + lg * 8]);
#pragma unroll
        for (int mf2 = 0; mf2 < 3; ++mf2) {
            f32x4 az = {};
#pragma unroll
            for (int kk = 0; kk < 2; ++kk)
                az = __builtin_amdgcn_mfma_f32_16x16x32_bf16(atf[mf2][kk], bu[kk], az, 0, 0, 0);
#pragma unroll
            for (int r = 0; r < 4; ++r) {
                int w = 16 * mf2 + lg * 4 + r;
                if (w < 33) {
                    float val = az[r] + gbl * cs[w];
                    float y = fmaxf(val * s1 + c1, 0.f);
                    out[((size_t)(nt0 + j) * V_ + w) * 64 + o] = f2bf(y);
                }
            }
        }
    }
}

// ---------------- stage B: 9x1 tconv (64->64) + BN2 (+res) + ReLU via MFMA ----------------
// Round-6/10 version (measured floor 47us): persistent t-march depth 4,
// double-buffered swizzled LDS, reg-staged issue-early/write-late, hoisted residual.
template <bool RES>
__global__ __launch_bounds__(256) void k_stageB_mfma(
    const unsigned short* __restrict__ z,   // [N,T,V,64] bf16 conv input
    unsigned short* __restrict__ out,       // [N,T,V,64] bf16 (residual source if RES)
    const unsigned short* __restrict__ wbf, // [9][64][64] bf16 [k][o][i]
    const float* __restrict__ tb,
    const float* __restrict__ g2, const float* __restrict__ b2,
    const float* __restrict__ m2, const float* __restrict__ vv2)
{
    __shared__ unsigned short sa[2][72 * 64];  // two swizzled tile buffers

    int bx = blockIdx.x, v = blockIdx.y, n = blockIdx.z;
    int base_t0 = bx * 256;                    // block covers t in [base_t0, base_t0+256)
    int tid = threadIdx.x;
    int wv = tid >> 6, lane = tid & 63;
    int l15 = lane & 15, lg = lane >> 4;
    int o = wv * 16 + l15;

    // preload 18 weight fragments into registers
    short8 bw[18];
#pragma unroll
    for (int k = 0; k < 9; ++k)
#pragma unroll
        for (int c = 0; c < 2; ++c)
            bw[k * 2 + c] = *reinterpret_cast<const short8*>(
                wbf + ((k * 64 + o) * 64) + c * 32 + lg * 8);

    float s2 = g2[o] * rsqrtf(vv2[o] + EPS_);
    float c2 = (tb[o] - m2[o]) * s2 + b2[o];

    // staging regs: each thread covers idx = tid, tid+256, tid+512 (<576)
    short8 stg[3];

#define LOADJ(jj)                                                             \
    {                                                                         \
        int t0l = base_t0 + (jj) * 64;                                        \
        _Pragma("unroll")                                                     \
        for (int it = 0; it < 3; ++it) {                                      \
            int idx = tid + it * 256;                                         \
            if (idx < 576) {                                                  \
                int r = idx >> 3;                                             \
                int tg = t0l - 4 + r;                                         \
                short8 val = {};                                              \
                if (tg >= 0 && tg < T_)                                       \
                    val = *reinterpret_cast<const short8*>(                   \
                        z + ((size_t)(n * T_ + tg) * V_ + v) * 64 +           \
                        (idx & 7) * 8);                                       \
                stg[it] = val;                                                \
            }                                                                 \
        }                                                                     \
    }

#define WRITEJ(pp)                                                            \
    {                                                                         \
        _Pragma("unroll")                                                     \
        for (int it = 0; it < 3; ++it) {                                      \
            int idx = tid + it * 256;                                         \
            if (idx < 576) {                                                  \
                int r = idx >> 3, cc = idx & 7;                               \
                int slot = cc ^ (r & 7);                                      \
                *reinterpret_cast<short8*>(                                   \
                    reinterpret_cast<char*>(&sa[pp][0]) + r * 128 +           \
                    slot * 16) = stg[it];                                     \
            }                                                                 \
        }                                                                     \
    }

    // prologue: stage tile 0 into buffer 0
    LOADJ(0);
    WRITEJ(0);
    __syncthreads();

    int p = 0;
    for (int j = 0; j < 4; ++j) {
        // issue next tile's global loads early (latency hides under compute)
        if (j < 3) LOADJ(j + 1);

        int t0 = base_t0 + j * 64;

        // hoist residual loads (same-thread RAW with own later store: safe)
        unsigned short res[16];
        if (RES) {
#pragma unroll
            for (int f = 0; f < 4; ++f)
#pragma unroll
                for (int r = 0; r < 4; ++r) {
                    int t = t0 + f * 16 + lg * 4 + r;
                    res[f * 4 + r] =
                        out[((size_t)(n * T_ + t) * V_ + v) * 64 + o];
                }
        }

        // compute tile j from sa[p]
        f32x4 acc[4] = {};
        for (int k = 0; k < 9; ++k) {
#pragma unroll
            for (int c = 0; c < 2; ++c) {
                short8 b = bw[k * 2 + c];
#pragma unroll
                for (int f = 0; f < 4; ++f) {
                    int r = f * 16 + l15 + k;
                    int slot = (c * 4 + lg) ^ (r & 7);
                    short8 a = *reinterpret_cast<const short8*>(
                        reinterpret_cast<const char*>(&sa[p][0]) + r * 128 + slot * 16);
                    acc[f] = __builtin_amdgcn_mfma_f32_16x16x32_bf16(a, b, acc[f], 0, 0, 0);
                }
            }
        }

        // epilogue for tile j
#pragma unroll
        for (int f = 0; f < 4; ++f) {
#pragma unroll
            for (int r = 0; r < 4; ++r) {
                int t = t0 + f * 16 + lg * 4 + r;
                size_t addr = ((size_t)(n * T_ + t) * V_ + v) * 64 + o;
                float zz = acc[f][r] * s2 + c2;
                if (RES) zz += bf2f(res[f * 4 + r]);
                out[addr] = f2bf(fmaxf(zz, 0.f));
            }
        }

        // write staged regs into the other buffer, then one barrier
        if (j < 3) WRITEJ(p ^ 1);
        __syncthreads();
        p ^= 1;
    }
#undef LOADJ
#undef WRITEJ
}

// ---------------- b5 stage A: gconv 64->3 + agg + BN1 + ReLU (bf16 in, f32 out) ----------
__global__ __launch_bounds__(256) void k_stageA_b5(
    const unsigned short* __restrict__ in,  // [N,T,V,64] bf16
    float* __restrict__ out,                // [N,T,V,3] f32
    const float* __restrict__ Adj,
    const float* __restrict__ gw,           // [3][64]
    const float* __restrict__ gb,
    const float* __restrict__ g1, const float* __restrict__ b1,
    const float* __restrict__ m1, const float* __restrict__ v1)
{
    __shared__ float sy[V_ * 64];
    __shared__ float su[V_ * 4];
    __shared__ float sA[V_ * V_];
    int nt = blockIdx.x;
    int tid = threadIdx.x;
    const unsigned short* src = in + (size_t)nt * (V_ * 64);
    for (int idx = tid; idx < 264; idx += 256) {
        short8 val = *reinterpret_cast<const short8*>(src + idx * 8);
#pragma unroll
        for (int e = 0; e < 8; ++e)
            sy[idx * 8 + e] = bf2f((unsigned short)val[e]);
    }
    for (int idx = tid; idx < V_ * V_; idx += 256) sA[idx] = Adj[idx];
    __syncthreads();
    for (int idx = tid; idx < V_ * 3; idx += 256) {
        int v = idx / 3, o = idx % 3;
        float a = gb[o];
        for (int c = 0; c < 64; ++c) a = fmaf(sy[v * 64 + c], gw[o * 64 + c], a);
        su[v * 4 + o] = a;
    }
    __syncthreads();
    for (int idx = tid; idx < V_ * 3; idx += 256) {
        int w = idx / 3, o = idx % 3;
        float a = 0.f;
        for (int vv = 0; vv < V_; ++vv) a = fmaf(su[vv * 4 + o], sA[vv * V_ + w], a);
        float s = g1[o] * rsqrtf(v1[o] + EPS_);
        float zz = (a - m1[o]) * s + b1[o];
        out[(size_t)nt * (V_ * 3) + w * 3 + o] = fmaxf(zz, 0.f);
    }
}

// ---------------- b5 stage B: tconv 3->3 + BN2 + ReLU, + raw x, write d_out ----------------
__global__ __launch_bounds__(256) void k_stageB_b5(
    const float* __restrict__ z5,   // [N,T,V,3]
    const float* __restrict__ x,    // [N,T,V,3]
    float* __restrict__ out,        // [N,T,V,3]
    const float* __restrict__ tw,   // [3][3][9]
    const float* __restrict__ tb,
    const float* __restrict__ g2, const float* __restrict__ b2,
    const float* __restrict__ m2, const float* __restrict__ v2)
{
    int idx = blockIdx.x * 256 + threadIdx.x;  // over N*T*V
    if (idx >= N_ * T_ * V_) return;
    int v = idx % V_;
    int t = (idx / V_) % T_;
    int n = idx / (V_ * T_);
    float acc0 = tb[0], acc1 = tb[1], acc2 = tb[2];
    for (int k = 0; k < 9; ++k) {
        int tg = t + k - 4;
        if (tg < 0 || tg >= T_) continue;
        const float* zp = &z5[((size_t)(n * T_ + tg) * V_ + v) * 3];
        float zi0 = zp[0], zi1 = zp[1], zi2 = zp[2];
        acc0 = fmaf(tw[0 * 9 + k], zi0, acc0);
        acc0 = fmaf(tw[1 * 9 + k], zi1, acc0);
        acc0 = fmaf(tw[2 * 9 + k], zi2, acc0);
        acc1 = fmaf(tw[3 * 9 + k], zi0, acc1);
        acc1 = fmaf(tw[4 * 9 + k], zi1, acc1);
        acc1 = fmaf(tw[5 * 9 + k], zi2, acc1);
        acc2 = fmaf(tw[6 * 9 + k], zi0, acc2);
        acc2 = fmaf(tw[7 * 9 + k], zi1, acc2);
        acc2 = fmaf(tw[8 * 9 + k], zi2, acc2);
    }
    size_t base = (size_t)idx * 3;
    float a[3] = {acc0, acc1, acc2};
#pragma unroll
    for (int oo = 0; oo < 3; ++oo) {
        float s = g2[oo] * rsqrtf(v2[oo] + EPS_);
        float zz = (a[oo] - m2[oo]) * s + b2[oo];
        out[base + oo] = x[base + oo] + fmaxf(zz, 0.f);
    }
}

extern "C" void kernel_launch(void* const* d_in, const int* in_sizes, int n_in,
                              void* d_out, int out_size, void* d_ws, size_t ws_size,
                              hipStream_t stream) {
    int a = 0;
    const float* x      = (const float*)d_in[a++];
    const float* Adj    = (const float*)d_in[a++];
    const float* dbn_g  = (const float*)d_in[a++];
    const float* dbn_b  = (const float*)d_in[a++];
    const float* dbn_m  = (const float*)d_in[a++];
    const float* dbn_v  = (const float*)d_in[a++];
    const float* b1_gw  = (const float*)d_in[a++];
    const float* b1_gb  = (const float*)d_in[a++];
    const float* b1_bn1g = (const float*)d_in[a++];
    const float* b1_bn1b = (const float*)d_in[a++];
    const float* b1_bn1m = (const float*)d_in[a++];
    const float* b1_bn1v = (const float*)d_in[a++];
    const float* b1_tw  = (const float*)d_in[a++];
    const float* b1_tb  = (const float*)d_in[a++];
    const float* b1_bn2g = (const float*)d_in[a++];
    const float* b1_bn2b = (const float*)d_in[a++];
    const float* b1_bn2m = (const float*)d_in[a++];
    const float* b1_bn2v = (const float*)d_in[a++];
    const float* m_gw   = (const float*)d_in[a++];
    const float* m_gb   = (const float*)d_in[a++];
    const float* m_bn1g = (const float*)d_in[a++];
    const float* m_bn1b = (const float*)d_in[a++];
    const float* m_bn1m = (const float*)d_in[a++];
    const float* m_bn1v = (const float*)d_in[a++];
    const float* m_tw   = (const float*)d_in[a++];
    const float* m_tb   = (const float*)d_in[a++];
    const float* m_bn2g = (const float*)d_in[a++];
    const float* m_bn2b = (const float*)d_in[a++];
    const float* m_bn2m = (const float*)d_in[a++];
    const float* m_bn2v = (const float*)d_in[a++];
    const float* b5_gw  = (const float*)d_in[a++];
    const float* b5_gb  = (const float*)d_in[a++];
    const float* b5_bn1g = (const float*)d_in[a++];
    const float* b5_bn1b = (const float*)d_in[a++];
    const float* b5_bn1m = (const float*)d_in[a++];
    const float* b5_bn1v = (const float*)d_in[a++];
    const float* b5_tw  = (const float*)d_in[a++];
    const float* b5_tb  = (const float*)d_in[a++];
    const float* b5_bn2g = (const float*)d_in[a++];
    const float* b5_bn2b = (const float*)d_in[a++];
    const float* b5_bn2m = (const float*)d_in[a++];
    const float* b5_bn2v = (const float*)d_in[a++];

    // ws layout (bytes, all 16B aligned)
    char* ws = (char*)d_ws;
    const size_t S_BIG_B  = (size_t)N_ * T_ * V_ * 64 * 2;   // bf16 big buffers
    const size_t S_SM_B   = (size_t)N_ * T_ * V_ * 3 * 4;    // f32 small buffers
    unsigned short* B0     = (unsigned short*)(ws);
    unsigned short* B1     = (unsigned short*)(ws + S_BIG_B);
    float*          z5     = (float*)(ws + 2 * S_BIG_B + S_SM_B);
    unsigned short* wT_bf  = (unsigned short*)(ws + 2 * S_BIG_B + 2 * S_SM_B);
    unsigned short* gw_bf  = wT_bf + 147456;
    unsigned short* ATbf   = gw_bf + 12288;
    float*          colsum = (float*)(ATbf + 3456);
    float*          gwT_b1 = colsum + 48;

    k_prep<<<(163440 + 255) / 256, 256, 0, stream>>>(
        b1_tw, m_tw, b1_gw, m_gw, Adj, wT_bf, gw_bf, ATbf, colsum, gwT_b1);

    // b1: 3 -> 64 (VALU gconv + MFMA agg, data_bn fused), no residual
    k_stageA_b1<<<(N_ * T_) / 4, 256, 0, stream>>>(
        x, B1, ATbf, colsum, gwT_b1, b1_gb, b1_bn1g, b1_bn1b, b1_bn1m, b1_bn1v,
        dbn_g, dbn_b, dbn_m, dbn_v);
    k_stageB_mfma<false><<<dim3(T_ / 256, V_, N_), 256, 0, stream>>>(
        B1, B0, wT_bf, b1_tb, b1_bn2g, b1_bn2b, b1_bn2m, b1_bn2v);

    // 3 mid blocks: 64 -> 64 MFMA, residual (in-place into B0)
    for (int i = 0; i < 3; ++i) {
        k_stageA_mfma<<<(N_ * T_) / 4, 256, 0, stream>>>(
            B0, B1, ATbf, colsum, gw_bf + i * 4096, m_gb + i * 64,
            m_bn1g + i * 64, m_bn1b + i * 64, m_bn1m + i * 64, m_bn1v + i * 64);
        k_stageB_mfma<true><<<dim3(T_ / 256, V_, N_), 256, 0, stream>>>(
            B1, B0, wT_bf + (1 + i) * 36864, m_tb + i * 64,
            m_bn2g + i * 64, m_bn2b + i * 64, m_bn2m + i * 64, m_bn2v + i * 64);
    }

    // b5: 64 -> 3, no residual; then + raw x, write d_out
    k_stageA_b5<<<N_ * T_, 256, 0, stream>>>(
        B0, z5, Adj, b5_gw, b5_gb, b5_bn1g, b5_bn1b, b5_bn1m, b5_bn1v);
    k_stageB_b5<<<(N_ * T_ * V_ + 255) / 256, 256, 0, stream>>>(
        z5, x, (float*)d_out, b5_tw, b5_tb, b5_bn2g, b5_bn2b, b5_bn2m, b5_bn2v);
}

// Round 19
// 254.301 us; speedup vs baseline: 1.1542x; 1.0629x over previous
//
#include <hip/hip_runtime.h>
#include <hip/hip_bf16.h>

// PoseRefinerModel: ST-GCN-like. bf16 MFMA datapath for gconv/agg/tconv.
// N=16 T=512 V=33 C=3 H=64, EPS=1e-5.
// Round 19 = round-18 (270.3us) + k_stageA_b5 rewritten with the same recipe
// that fixed b1A: MFMA GEMM1 (gw zero-padded to 16 cols) + MFMA aggregation
// (atf frags, colsum bias, wave-private UT rows wv*16+l15, barrier-free).
// Each wave owns one nt (j=wv). prep gains gwpad_b5 [16][64] bf16.
// stageB / stageA_mfma / b1A / b5B byte-identical to round 18.

constexpr int N_ = 16, T_ = 512, V_ = 33, C_ = 3, H_ = 64;
constexpr float EPS_ = 1e-5f;

typedef __attribute__((ext_vector_type(8))) short short8;
typedef __attribute__((ext_vector_type(4))) float f32x4;

__device__ inline unsigned short f2bf(float f) {
    union { __hip_bfloat16 h; unsigned short u; } cv;
    cv.h = __float2bfloat16(f);
    return cv.u;
}
__device__ inline float bf2f(unsigned short u) {
    union { unsigned short u; __hip_bfloat16 h; } cv;
    cv.u = u;
    return __bfloat162float(cv.h);
}

// ---------------- prep: bf16 weight re-layouts + padded bf16 adjacency ----------------
__global__ __launch_bounds__(256) void k_prep(
    const float* __restrict__ b1_tw, const float* __restrict__ m_tw,
    const float* __restrict__ b1_gw, const float* __restrict__ m_gw,
    const float* __restrict__ b5_gw,
    const float* __restrict__ Adj,
    unsigned short* __restrict__ wT_bf, unsigned short* __restrict__ gw_bf,
    unsigned short* __restrict__ ATbf, float* __restrict__ colsum,
    float* __restrict__ gwT_b1, unsigned short* __restrict__ gwpad_b5)
{
    int idx = blockIdx.x * 256 + threadIdx.x;
    if (idx < 147456) {
        int s = idx / 36864, r = idx % 36864;
        int k = r / 4096, o = (r % 4096) / 64, i = r % 64;
        const float* src = (s == 0) ? b1_tw : (m_tw + (size_t)(s - 1) * 36864);
        wT_bf[idx] = f2bf(src[(o * 64 + i) * 9 + k]);
    } else if (idx < 147456 + 12288) {
        int r = idx - 147456;
        gw_bf[r] = f2bf(m_gw[r]);                 // already [s][o][c]
    } else if (idx < 147456 + 12288 + 3456) {
        int r = idx - 159744;
        int w = r / 72, vv = r % 72;
        ATbf[r] = (w < 33 && vv < 33) ? f2bf(Adj[vv * 33 + w]) : (unsigned short)0;
    } else if (idx < 147456 + 12288 + 3456 + 48) {
        int w = idx - 163200;
        float s = 0.f;
        if (w < 33)
            for (int vv = 0; vv < 33; ++vv) s += Adj[vv * 33 + w];
        colsum[w] = s;
    } else if (idx < 147456 + 12288 + 3456 + 48 + 192) {
        int r = idx - 163248;
        int c = r / 64, o = r % 64;
        gwT_b1[r] = b1_gw[o * 3 + c];
    } else if (idx < 147456 + 12288 + 3456 + 48 + 192 + 1024) {
        int r = idx - 163440;
        int o16 = r / 64, c = r % 64;
        gwpad_b5[r] = (o16 < 3) ? f2bf(b5_gw[o16 * 64 + c]) : (unsigned short)0;
    }
}

// ---------------- b1 stage A (+fused data_bn): gconv 3->64 + MFMA agg + BN1 + ReLU ----
// 4 (n,t) per block, 4 waves (each owns a 16-wide o slice). (round-18 version)
__global__ __launch_bounds__(256) void k_stageA_b1(
    const float* __restrict__ x,    // [N,T,V,3] f32 RAW input (data_bn applied inline)
    unsigned short* __restrict__ out, // [N,T,V,64] bf16
    const unsigned short* __restrict__ ATbf, // [48][72] bf16
    const float* __restrict__ colsum,        // [48]
    const float* __restrict__ gwT,  // [3][64] f32 (c-major)
    const float* __restrict__ gb,
    const float* __restrict__ g1, const float* __restrict__ b1,
    const float* __restrict__ m1, const float* __restrict__ v1,
    const float* __restrict__ dg, const float* __restrict__ db,
    const float* __restrict__ dm, const float* __restrict__ dv)
{
    __shared__ float sy[4][V_ * 4];          // [j][v*4+c] data_bn'd input
    __shared__ unsigned short UT[64 * 72];   // [o][v] bf16, wave-private rows
    __shared__ float cs[48];

    int nt0 = blockIdx.x * 4;
    int tid = threadIdx.x;
    int wv = tid >> 6, lane = tid & 63;
    int l15 = lane & 15, lg = lane >> 4;
    int o = wv * 16 + l15;

    short8 atf[3][2];
#pragma unroll
    for (int mf = 0; mf < 3; ++mf)
#pragma unroll
        for (int kk = 0; kk < 2; ++kk)
            atf[mf][kk] = *reinterpret_cast<const short8*>(
                ATbf + (16 * mf + l15) * 72 + kk * 32 + lg * 8);

    float gw0 = gwT[0 * 64 + o], gw1 = gwT[1 * 64 + o], gw2 = gwT[2 * 64 + o];
    float gbl = gb[o];
    float s1 = g1[o] * rsqrtf(v1[o] + EPS_);
    float c1 = b1[o] - m1[o] * s1;

    for (int idx = tid; idx < 4 * V_ * 3; idx += 256) {
        int j = idx / (V_ * 3), r = idx % (V_ * 3);
        int v = r / 3, c = r % 3;
        int nt = nt0 + j;
        int t = nt & (T_ - 1);
        int jj = c * V_ + ((t * V_ + v) >> 9);
        float s = dg[jj] * rsqrtf(dv[jj] + EPS_);
        sy[j][v * 4 + c] = (x[(size_t)nt * (V_ * 3) + r] - dm[jj]) * s + db[jj];
    }
    for (int idx = tid; idx < 128; idx += 256) {
        int oo = idx >> 1, cc = idx & 1;
        short8 z = {};
        *reinterpret_cast<short8*>(&UT[oo * 72 + 48 + cc * 8]) = z;
    }
    if (tid < 48) cs[tid] = colsum[tid];
    __syncthreads();   // the ONLY block-wide barrier

    for (int j = 0; j < 4; ++j) {
#pragma unroll
        for (int it = 0; it < 12; ++it) {
            int v = lg + it * 4;
            float u = 0.f;
            if (v < V_) {
                u = sy[j][v * 4 + 0] * gw0;
                u = fmaf(sy[j][v * 4 + 1], gw1, u);
                u = fmaf(sy[j][v * 4 + 2], gw2, u);
            }
            UT[o * 72 + v] = f2bf(u);
        }
        short8 bu[2];
#pragma unroll
        for (int kk = 0; kk < 2; ++kk)
            bu[kk] = *reinterpret_cast<const short8*>(&UT[o * 72 + kk * 32 + lg * 8]);
#pragma unroll
        for (int mf2 = 0; mf2 < 3; ++mf2) {
            f32x4 az = {};
#pragma unroll
            for (int kk = 0; kk < 2; ++kk)
                az = __builtin_amdgcn_mfma_f32_16x16x32_bf16(atf[mf2][kk], bu[kk], az, 0, 0, 0);
#pragma unroll
            for (int r = 0; r < 4; ++r) {
                int w = 16 * mf2 + lg * 4 + r;
                if (w < 33) {
                    float val = az[r] + gbl * cs[w];
                    float y = fmaxf(val * s1 + c1, 0.f);
                    out[((size_t)(nt0 + j) * V_ + w) * 64 + o] = f2bf(y);
                }
            }
        }
    }
}

// ---------------- mid stage A: gconv 64->64 + agg + BN1 + ReLU via MFMA ----------------
// 4 (n,t) pairs per block, 4 waves (each owns a 16-wide o slice). (round-14 version)
__global__ __launch_bounds__(256) void k_stageA_mfma(
    const unsigned short* __restrict__ in,   // [N,T,V,64] bf16
    unsigned short* __restrict__ out,        // [N,T,V,64] bf16
    const unsigned short* __restrict__ ATbf, // [48][72] bf16
    const float* __restrict__ colsum,        // [48]
    const unsigned short* __restrict__ gwbf, // [64][64] bf16 [o][c]
    const float* __restrict__ gb,
    const float* __restrict__ g1, const float* __restrict__ b1,
    const float* __restrict__ m1, const float* __restrict__ v1)
{
    __shared__ unsigned short Ys[4 * 48 * 72];
    __shared__ unsigned short UT[64 * 72];
    __shared__ float cs[48];

    int nt0 = blockIdx.x * 4;
    int tid = threadIdx.x;
    int wv = tid >> 6, lane = tid & 63;
    int l15 = lane & 15, lg = lane >> 4;
    int o = wv * 16 + l15;

    short8 atf[3][2];
#pragma unroll
    for (int mf = 0; mf < 3; ++mf)
#pragma unroll
        for (int kk = 0; kk < 2; ++kk)
            atf[mf][kk] = *reinterpret_cast<const short8*>(
                ATbf + (16 * mf + l15) * 72 + kk * 32 + lg * 8);
    short8 gwf[2];
#pragma unroll
    for (int kk = 0; kk < 2; ++kk)
        gwf[kk] = *reinterpret_cast<const short8*>(gwbf + o * 64 + kk * 32 + lg * 8);

    float gbl = gb[o];
    float s1 = g1[o] * rsqrtf(v1[o] + EPS_);
    float c1 = b1[o] - m1[o] * s1;

    for (int idx = tid; idx < 1056; idx += 256) {
        int j = idx / 264, r = idx % 264;
        int v = r >> 3, cc = r & 7;
        *reinterpret_cast<short8*>(&Ys[(j * 48 + v) * 72 + cc * 8]) =
            *reinterpret_cast<const short8*>(in + ((size_t)(nt0 + j) * V_ + v) * 64 + cc * 8);
    }
    for (int idx = tid; idx < 540; idx += 256) {
        int j = idx / 135, r = idx % 135;
        int v = 33 + r / 9, cc = r % 9;
        short8 z = {};
        *reinterpret_cast<short8*>(&Ys[(j * 48 + v) * 72 + cc * 8]) = z;
    }
    for (int idx = tid; idx < 128; idx += 256) {
        int oo = idx >> 1, cc = idx & 1;
        short8 z = {};
        *reinterpret_cast<short8*>(&UT[oo * 72 + 48 + cc * 8]) = z;
    }
    if (tid < 48) cs[tid] = colsum[tid];
    __syncthreads();   // the ONLY block-wide barrier

    for (int j = 0; j < 4; ++j) {
#pragma unroll
        for (int mf = 0; mf < 3; ++mf) {
            f32x4 au = {};
#pragma unroll
            for (int kk = 0; kk < 2; ++kk) {
                short8 a = *reinterpret_cast<const short8*>(
                    &Ys[(j * 48 + 16 * mf + l15) * 72 + kk * 32 + lg * 8]);
                au = __builtin_amdgcn_mfma_f32_16x16x32_bf16(a, gwf[kk], au, 0, 0, 0);
            }
            unsigned short pk[4];
            pk[0] = f2bf(au[0]); pk[1] = f2bf(au[1]);
            pk[2] = f2bf(au[2]); pk[3] = f2bf(au[3]);
            *reinterpret_cast<ushort4*>(&UT[o * 72 + 16 * mf + lg * 4]) =
                *reinterpret_cast<ushort4*>(pk);
        }
        short8 bu[2];
#pragma unroll
        for (int kk = 0; kk < 2; ++kk)
            bu[kk] = *reinterpret_cast<const short8*>(&UT[o * 72 + kk * 32 + lg * 8]);
#pragma unroll
        for (int mf2 = 0; mf2 < 3; ++mf2) {
            f32x4 az = {};
#pragma unroll
            for (int kk = 0; kk < 2; ++kk)
                az = __builtin_amdgcn_mfma_f32_16x16x32_bf16(atf[mf2][kk], bu[kk], az, 0, 0, 0);
#pragma unroll
            for (int r = 0; r < 4; ++r) {
                int w = 16 * mf2 + lg * 4 + r;
                if (w < 33) {
                    float val = az[r] + gbl * cs[w];
                    float y = fmaxf(val * s1 + c1, 0.f);
                    out[((size_t)(nt0 + j) * V_ + w) * 64 + o] = f2bf(y);
                }
            }
        }
    }
}

// ---------------- stage B: 9x1 tconv (64->64) + BN2 (+res) + ReLU via MFMA ----------------
// Round-6/10 version (measured floor 47us): persistent t-march depth 4,
// double-buffered swizzled LDS, reg-staged issue-early/write-late, hoisted residual.
template <bool RES>
__global__ __launch_bounds__(256) void k_stageB_mfma(
    const unsigned short* __restrict__ z,   // [N,T,V,64] bf16 conv input
    unsigned short* __restrict__ out,       // [N,T,V,64] bf16 (residual source if RES)
    const unsigned short* __restrict__ wbf, // [9][64][64] bf16 [k][o][i]
    const float* __restrict__ tb,
    const float* __restrict__ g2, const float* __restrict__ b2,
    const float* __restrict__ m2, const float* __restrict__ vv2)
{
    __shared__ unsigned short sa[2][72 * 64];  // two swizzled tile buffers

    int bx = blockIdx.x, v = blockIdx.y, n = blockIdx.z;
    int base_t0 = bx * 256;                    // block covers t in [base_t0, base_t0+256)
    int tid = threadIdx.x;
    int wv = tid >> 6, lane = tid & 63;
    int l15 = lane & 15, lg = lane >> 4;
    int o = wv * 16 + l15;

    short8 bw[18];
#pragma unroll
    for (int k = 0; k < 9; ++k)
#pragma unroll
        for (int c = 0; c < 2; ++c)
            bw[k * 2 + c] = *reinterpret_cast<const short8*>(
                wbf + ((k * 64 + o) * 64) + c * 32 + lg * 8);

    float s2 = g2[o] * rsqrtf(vv2[o] + EPS_);
    float c2 = (tb[o] - m2[o]) * s2 + b2[o];

    short8 stg[3];

#define LOADJ(jj)                                                             \
    {                                                                         \
        int t0l = base_t0 + (jj) * 64;                                        \
        _Pragma("unroll")                                                     \
        for (int it = 0; it < 3; ++it) {                                      \
            int idx = tid + it * 256;                                         \
            if (idx < 576) {                                                  \
                int r = idx >> 3;                                             \
                int tg = t0l - 4 + r;                                         \
                short8 val = {};                                              \
                if (tg >= 0 && tg < T_)                                       \
                    val = *reinterpret_cast<const short8*>(                   \
                        z + ((size_t)(n * T_ + tg) * V_ + v) * 64 +           \
                        (idx & 7) * 8);                                       \
                stg[it] = val;                                                \
            }                                                                 \
        }                                                                     \
    }

#define WRITEJ(pp)                                                            \
    {                                                                         \
        _Pragma("unroll")                                                     \
        for (int it = 0; it < 3; ++it) {                                      \
            int idx = tid + it * 256;                                         \
            if (idx < 576) {                                                  \
                int r = idx >> 3, cc = idx & 7;                               \
                int slot = cc ^ (r & 7);                                      \
                *reinterpret_cast<short8*>(                                   \
                    reinterpret_cast<char*>(&sa[pp][0]) + r * 128 +           \
                    slot * 16) = stg[it];                                     \
            }                                                                 \
        }                                                                     \
    }

    LOADJ(0);
    WRITEJ(0);
    __syncthreads();

    int p = 0;
    for (int j = 0; j < 4; ++j) {
        if (j < 3) LOADJ(j + 1);

        int t0 = base_t0 + j * 64;

        unsigned short res[16];
        if (RES) {
#pragma unroll
            for (int f = 0; f < 4; ++f)
#pragma unroll
                for (int r = 0; r < 4; ++r) {
                    int t = t0 + f * 16 + lg * 4 + r;
                    res[f * 4 + r] =
                        out[((size_t)(n * T_ + t) * V_ + v) * 64 + o];
                }
        }

        f32x4 acc[4] = {};
        for (int k = 0; k < 9; ++k) {
#pragma unroll
            for (int c = 0; c < 2; ++c) {
                short8 b = bw[k * 2 + c];
#pragma unroll
                for (int f = 0; f < 4; ++f) {
                    int r = f * 16 + l15 + k;
                    int slot = (c * 4 + lg) ^ (r & 7);
                    short8 a = *reinterpret_cast<const short8*>(
                        reinterpret_cast<const char*>(&sa[p][0]) + r * 128 + slot * 16);
                    acc[f] = __builtin_amdgcn_mfma_f32_16x16x32_bf16(a, b, acc[f], 0, 0, 0);
                }
            }
        }

#pragma unroll
        for (int f = 0; f < 4; ++f) {
#pragma unroll
            for (int r = 0; r < 4; ++r) {
                int t = t0 + f * 16 + lg * 4 + r;
                size_t addr = ((size_t)(n * T_ + t) * V_ + v) * 64 + o;
                float zz = acc[f][r] * s2 + c2;
                if (RES) zz += bf2f(res[f * 4 + r]);
                out[addr] = f2bf(fmaxf(zz, 0.f));
            }
        }

        if (j < 3) WRITEJ(p ^ 1);
        __syncthreads();
        p ^= 1;
    }
#undef LOADJ
#undef WRITEJ
}

// ---------------- b5 stage A: gconv 64->3 + agg + BN1 + ReLU via MFMA ----------------
// 4 nt per block; wave j=wv owns one nt. GEMM1 with gw zero-padded to [16][64];
// UT rows wv*16+l15 wave-private (barrier-free); GEMM2 = adjacency agg + colsum
// bias; epilogue stores f32 to z5 for l15<3, w<33.
__global__ __launch_bounds__(256) void k_stageA_b5(
    const unsigned short* __restrict__ in,   // [N,T,V,64] bf16
    float* __restrict__ out,                 // [N,T,V,3] f32
    const unsigned short* __restrict__ ATbf, // [48][72] bf16
    const float* __restrict__ colsum,        // [48]
    const unsigned short* __restrict__ gwpad,// [16][64] bf16 (rows 3..15 zero)
    const float* __restrict__ gb,            // [3]
    const float* __restrict__ g1, const float* __restrict__ b1,
    const float* __restrict__ m1, const float* __restrict__ v1)
{
    __shared__ unsigned short Ys[4 * 48 * 72];
    __shared__ unsigned short UT[64 * 72];
    __shared__ float cs[48];

    int nt0 = blockIdx.x * 4;
    int tid = threadIdx.x;
    int wv = tid >> 6, lane = tid & 63;
    int l15 = lane & 15, lg = lane >> 4;
    int urow = wv * 16 + l15;            // wave-private UT row

    short8 atf[3][2];
#pragma unroll
    for (int mf = 0; mf < 3; ++mf)
#pragma unroll
        for (int kk = 0; kk < 2; ++kk)
            atf[mf][kk] = *reinterpret_cast<const short8*>(
                ATbf + (16 * mf + l15) * 72 + kk * 32 + lg * 8);
    short8 gwf[2];
#pragma unroll
    for (int kk = 0; kk < 2; ++kk)
        gwf[kk] = *reinterpret_cast<const short8*>(gwpad + l15 * 64 + kk * 32 + lg * 8);

    float gbl = 0.f, s1 = 0.f, c1 = 0.f;
    if (l15 < 3) {
        gbl = gb[l15];
        s1 = g1[l15] * rsqrtf(v1[l15] + EPS_);
        c1 = b1[l15] - m1[l15] * s1;
    }

    // stage Ys (4 nt x 33 rows x 64 ch), pad rows 33..47 with zeros
    for (int idx = tid; idx < 1056; idx += 256) {
        int j = idx / 264, r = idx % 264;
        int v = r >> 3, cc = r & 7;
        *reinterpret_cast<short8*>(&Ys[(j * 48 + v) * 72 + cc * 8]) =
            *reinterpret_cast<const short8*>(in + ((size_t)(nt0 + j) * V_ + v) * 64 + cc * 8);
    }
    for (int idx = tid; idx < 540; idx += 256) {
        int j = idx / 135, r = idx % 135;
        int v = 33 + r / 9, cc = r % 9;
        short8 z = {};
        *reinterpret_cast<short8*>(&Ys[(j * 48 + v) * 72 + cc * 8]) = z;
    }
    // zero UT v=48..63 (K-pad)
    for (int idx = tid; idx < 128; idx += 256) {
        int oo = idx >> 1, cc = idx & 1;
        short8 z = {};
        *reinterpret_cast<short8*>(&UT[oo * 72 + 48 + cc * 8]) = z;
    }
    if (tid < 48) cs[tid] = colsum[tid];
    __syncthreads();   // the ONLY block-wide barrier

    int j = wv;   // this wave's nt
    // GEMM1: U[v][o16] = sum_c Y[v][c] * gwpad[o16][c]; UT rows wave-private.
#pragma unroll
    for (int mf = 0; mf < 3; ++mf) {
        f32x4 au = {};
#pragma unroll
        for (int kk = 0; kk < 2; ++kk) {
            short8 a = *reinterpret_cast<const short8*>(
                &Ys[(j * 48 + 16 * mf + l15) * 72 + kk * 32 + lg * 8]);
            au = __builtin_amdgcn_mfma_f32_16x16x32_bf16(a, gwf[kk], au, 0, 0, 0);
        }
        unsigned short pk[4];
        pk[0] = f2bf(au[0]); pk[1] = f2bf(au[1]);
        pk[2] = f2bf(au[2]); pk[3] = f2bf(au[3]);
        *reinterpret_cast<ushort4*>(&UT[urow * 72 + 16 * mf + lg * 4]) =
            *reinterpret_cast<ushort4*>(pk);
    }
    // GEMM2: Z[w][o16] = sum_v AT[w][v] * U[v][o16]
    short8 bu[2];
#pragma unroll
    for (int kk = 0; kk < 2; ++kk)
        bu[kk] = *reinterpret_cast<const short8*>(&UT[urow * 72 + kk * 32 + lg * 8]);
#pragma unroll
    for (int mf2 = 0; mf2 < 3; ++mf2) {
        f32x4 az = {};
#pragma unroll
        for (int kk = 0; kk < 2; ++kk)
            az = __builtin_amdgcn_mfma_f32_16x16x32_bf16(atf[mf2][kk], bu[kk], az, 0, 0, 0);
#pragma unroll
        for (int r = 0; r < 4; ++r) {
            int w = 16 * mf2 + lg * 4 + r;
            if (w < 33 && l15 < 3) {
                float val = az[r] + gbl * cs[w];
                float y = fmaxf(val * s1 + c1, 0.f);
                out[(size_t)(nt0 + j) * (V_ * 3) + w * 3 + l15] = y;
            }
        }
    }
}

// ---------------- b5 stage B: tconv 3->3 + BN2 + ReLU, + raw x, write d_out ----------------
__global__ __launch_bounds__(256) void k_stageB_b5(
    const float* __restrict__ z5,   // [N,T,V,3]
    const float* __restrict__ x,    // [N,T,V,3]
    float* __restrict__ out,        // [N,T,V,3]
    const float* __restrict__ tw,   // [3][3][9]
    const float* __restrict__ tb,
    const float* __restrict__ g2, const float* __restrict__ b2,
    const float* __restrict__ m2, const float* __restrict__ v2)
{
    int idx = blockIdx.x * 256 + threadIdx.x;  // over N*T*V
    if (idx >= N_ * T_ * V_) return;
    int v = idx % V_;
    int t = (idx / V_) % T_;
    int n = idx / (V_ * T_);
    float acc0 = tb[0], acc1 = tb[1], acc2 = tb[2];
    for (int k = 0; k < 9; ++k) {
        int tg = t + k - 4;
        if (tg < 0 || tg >= T_) continue;
        const float* zp = &z5[((size_t)(n * T_ + tg) * V_ + v) * 3];
        float zi0 = zp[0], zi1 = zp[1], zi2 = zp[2];
        acc0 = fmaf(tw[0 * 9 + k], zi0, acc0);
        acc0 = fmaf(tw[1 * 9 + k], zi1, acc0);
        acc0 = fmaf(tw[2 * 9 + k], zi2, acc0);
        acc1 = fmaf(tw[3 * 9 + k], zi0, acc1);
        acc1 = fmaf(tw[4 * 9 + k], zi1, acc1);
        acc1 = fmaf(tw[5 * 9 + k], zi2, acc1);
        acc2 = fmaf(tw[6 * 9 + k], zi0, acc2);
        acc2 = fmaf(tw[7 * 9 + k], zi1, acc2);
        acc2 = fmaf(tw[8 * 9 + k], zi2, acc2);
    }
    size_t base = (size_t)idx * 3;
    float a[3] = {acc0, acc1, acc2};
#pragma unroll
    for (int oo = 0; oo < 3; ++oo) {
        float s = g2[oo] * rsqrtf(v2[oo] + EPS_);
        float zz = (a[oo] - m2[oo]) * s + b2[oo];
        out[base + oo] = x[base + oo] + fmaxf(zz, 0.f);
    }
}

extern "C" void kernel_launch(void* const* d_in, const int* in_sizes, int n_in,
                              void* d_out, int out_size, void* d_ws, size_t ws_size,
                              hipStream_t stream) {
    int a = 0;
    const float* x      = (const float*)d_in[a++];
    const float* Adj    = (const float*)d_in[a++];
    const float* dbn_g  = (const float*)d_in[a++];
    const float* dbn_b  = (const float*)d_in[a++];
    const float* dbn_m  = (const float*)d_in[a++];
    const float* dbn_v  = (const float*)d_in[a++];
    const float* b1_gw  = (const float*)d_in[a++];
    const float* b1_gb  = (const float*)d_in[a++];
    const float* b1_bn1g = (const float*)d_in[a++];
    const float* b1_bn1b = (const float*)d_in[a++];
    const float* b1_bn1m = (const float*)d_in[a++];
    const float* b1_bn1v = (const float*)d_in[a++];
    const float* b1_tw  = (const float*)d_in[a++];
    const float* b1_tb  = (const float*)d_in[a++];
    const float* b1_bn2g = (const float*)d_in[a++];
    const float* b1_bn2b = (const float*)d_in[a++];
    const float* b1_bn2m = (const float*)d_in[a++];
    const float* b1_bn2v = (const float*)d_in[a++];
    const float* m_gw   = (const float*)d_in[a++];
    const float* m_gb   = (const float*)d_in[a++];
    const float* m_bn1g = (const float*)d_in[a++];
    const float* m_bn1b = (const float*)d_in[a++];
    const float* m_bn1m = (const float*)d_in[a++];
    const float* m_bn1v = (const float*)d_in[a++];
    const float* m_tw   = (const float*)d_in[a++];
    const float* m_tb   = (const float*)d_in[a++];
    const float* m_bn2g = (const float*)d_in[a++];
    const float* m_bn2b = (const float*)d_in[a++];
    const float* m_bn2m = (const float*)d_in[a++];
    const float* m_bn2v = (const float*)d_in[a++];
    const float* b5_gw  = (const float*)d_in[a++];
    const float* b5_gb  = (const float*)d_in[a++];
    const float* b5_bn1g = (const float*)d_in[a++];
    const float* b5_bn1b = (const float*)d_in[a++];
    const float* b5_bn1m = (const float*)d_in[a++];
    const float* b5_bn1v = (const float*)d_in[a++];
    const float* b5_tw  = (const float*)d_in[a++];
    const float* b5_tb  = (const float*)d_in[a++];
    const float* b5_bn2g = (const float*)d_in[a++];
    const float* b5_bn2b = (const float*)d_in[a++];
    const float* b5_bn2m = (const float*)d_in[a++];
    const float* b5_bn2v = (const float*)d_in[a++];

    // ws layout (bytes, all 16B aligned)
    char* ws = (char*)d_ws;
    const size_t S_BIG_B  = (size_t)N_ * T_ * V_ * 64 * 2;   // bf16 big buffers
    const size_t S_SM_B   = (size_t)N_ * T_ * V_ * 3 * 4;    // f32 small buffers
    unsigned short* B0     = (unsigned short*)(ws);
    unsigned short* B1     = (unsigned short*)(ws + S_BIG_B);
    float*          z5     = (float*)(ws + 2 * S_BIG_B + S_SM_B);
    unsigned short* wT_bf  = (unsigned short*)(ws + 2 * S_BIG_B + 2 * S_SM_B);
    unsigned short* gw_bf  = wT_bf + 147456;
    unsigned short* ATbf   = gw_bf + 12288;
    float*          colsum = (float*)(ATbf + 3456);
    float*          gwT_b1 = colsum + 48;
    unsigned short* gwpad_b5 = (unsigned short*)(gwT_b1 + 192);

    k_prep<<<(164464 + 255) / 256, 256, 0, stream>>>(
        b1_tw, m_tw, b1_gw, m_gw, b5_gw, Adj,
        wT_bf, gw_bf, ATbf, colsum, gwT_b1, gwpad_b5);

    // b1: 3 -> 64 (VALU gconv + MFMA agg, data_bn fused), no residual
    k_stageA_b1<<<(N_ * T_) / 4, 256, 0, stream>>>(
        x, B1, ATbf, colsum, gwT_b1, b1_gb, b1_bn1g, b1_bn1b, b1_bn1m, b1_bn1v,
        dbn_g, dbn_b, dbn_m, dbn_v);
    k_stageB_mfma<false><<<dim3(T_ / 256, V_, N_), 256, 0, stream>>>(
        B1, B0, wT_bf, b1_tb, b1_bn2g, b1_bn2b, b1_bn2m, b1_bn2v);

    // 3 mid blocks: 64 -> 64 MFMA, residual (in-place into B0)
    for (int i = 0; i < 3; ++i) {
        k_stageA_mfma<<<(N_ * T_) / 4, 256, 0, stream>>>(
            B0, B1, ATbf, colsum, gw_bf + i * 4096, m_gb + i * 64,
            m_bn1g + i * 64, m_bn1b + i * 64, m_bn1m + i * 64, m_bn1v + i * 64);
        k_stageB_mfma<true><<<dim3(T_ / 256, V_, N_), 256, 0, stream>>>(
            B1, B0, wT_bf + (1 + i) * 36864, m_tb + i * 64,
            m_bn2g + i * 64, m_bn2b + i * 64, m_bn2m + i * 64, m_bn2v + i * 64);
    }

    // b5: 64 -> 3 (MFMA, 4 nt/block), no residual; then + raw x, write d_out
    k_stageA_b5<<<(N_ * T_) / 4, 256, 0, stream>>>(
        B0, z5, ATbf, colsum, gwpad_b5, b5_gb,
        b5_bn1g, b5_bn1b, b5_bn1m, b5_bn1v);
    k_stageB_b5<<<(N_ * T_ * V_ + 255) / 256, 256, 0, stream>>>(
        z5, x, (float*)d_out, b5_tw, b5_tb, b5_bn2g, b5_bn2b, b5_bn2m, b5_bn2v);
}